// Round 1
// baseline (48.724 us; speedup 1.0000x reference)
//
#include <hip/hip_runtime.h>
#include <hip/hip_bf16.h>
#include <math.h>

// Problem constants (fixed by the reference setup_inputs)
#define NROWS 2048
#define KROWS 256
#define DDIM  512

// Workspace layout (in floats):
//   P  [K][D]  : p_poincare
//   A  [K][D]  : a_poincare
//   SC [K][4]  : {p2, pa, na, kc} per k
//   Y2 [N]     : ||x_n||^2
#define WS_P   0
#define WS_A   (KROWS * DDIM)                 // 131072
#define WS_SC  (2 * KROWS * DDIM)             // 262144
#define WS_Y2  (2 * KROWS * DDIM + 4 * KROWS) // 263168
// total = 265216 floats ~= 1.04 MB

__device__ inline float wave_reduce_sum(float v) {
    // full 64-lane butterfly
    #pragma unroll
    for (int off = 32; off > 0; off >>= 1)
        v += __shfl_xor(v, off, 64);
    return v;
}

// One wave per k (blocks 0..63) or per x-row (blocks 64..575).
__global__ __launch_bounds__(256) void hmlr_prep(
        const float* __restrict__ x,
        const float* __restrict__ a_vals,
        const float* __restrict__ p_vals,
        float* __restrict__ ws) {
    const int tid  = threadIdx.x;
    const int w    = tid >> 6;
    const int lane = tid & 63;
    const int bid  = blockIdx.x;

    if (bid < 64) {
        const int k = bid * 4 + w;  // 0..255
        const float4* pv4 = (const float4*)(p_vals) + k * (DDIM / 4) + lane * 2;
        const float4* av4 = (const float4*)(a_vals) + k * (DDIM / 4) + lane * 2;
        float4 p0 = pv4[0], p1 = pv4[1];
        float4 a0 = av4[0], a1 = av4[1];

        float pn2 = p0.x*p0.x + p0.y*p0.y + p0.z*p0.z + p0.w*p0.w
                  + p1.x*p1.x + p1.y*p1.y + p1.z*p1.z + p1.w*p1.w;
        float an2 = a0.x*a0.x + a0.y*a0.y + a0.z*a0.z + a0.w*a0.w
                  + a1.x*a1.x + a1.y*a1.y + a1.z*a1.z + a1.w*a1.w;
        float pa0 = p0.x*a0.x + p0.y*a0.y + p0.z*a0.z + p0.w*a0.w
                  + p1.x*a1.x + p1.y*a1.y + p1.z*a1.z + p1.w*a1.w;

        pn2 = wave_reduce_sum(pn2);
        an2 = wave_reduce_sum(an2);
        pa0 = wave_reduce_sum(pa0);

        // expmap0 with c = 1: p = tanh(clamp(||u||,15)) * u / ||u||
        float u     = fmaxf(sqrtf(pn2), 1e-5f);
        float t     = tanhf(fminf(u, 15.0f));
        float scale = t / u;
        float p2    = scale * scale * pn2;       // ||p_poincare||^2
        float conf  = 1.0f - p2;                 // conformal factor (c=1)
        float na    = fmaxf(conf * sqrtf(an2), 1e-7f);  // max(||a_poincare||, 1e-7)
        float pa    = scale * conf * pa0;        // dot(p_poincare, a_poincare)
        float lam   = 2.0f / (1.0f - fminf(p2, 0.9999f)); // 1/c - 1e-4 = 0.9999
        float kc    = lam * na;                  // / sqrt(c) = 1

        float4* P4 = (float4*)(ws + WS_P + k * DDIM) + lane * 2;
        float4* A4 = (float4*)(ws + WS_A + k * DDIM) + lane * 2;
        P4[0] = make_float4(scale*p0.x, scale*p0.y, scale*p0.z, scale*p0.w);
        P4[1] = make_float4(scale*p1.x, scale*p1.y, scale*p1.z, scale*p1.w);
        A4[0] = make_float4(conf*a0.x, conf*a0.y, conf*a0.z, conf*a0.w);
        A4[1] = make_float4(conf*a1.x, conf*a1.y, conf*a1.z, conf*a1.w);
        if (lane == 0)
            ((float4*)(ws + WS_SC))[k] = make_float4(p2, pa, na, kc);
    } else {
        const int row = (bid - 64) * 4 + w;  // 0..2047
        const float4* xv4 = (const float4*)(x) + row * (DDIM / 4) + lane * 2;
        float4 x0 = xv4[0], x1 = xv4[1];
        float s = x0.x*x0.x + x0.y*x0.y + x0.z*x0.z + x0.w*x0.w
                + x1.x*x1.x + x1.y*x1.y + x1.z*x1.z + x1.w*x1.w;
        s = wave_reduce_sum(s);
        if (lane == 0) ws[WS_Y2 + row] = s;
    }
}

// Main fused kernel: 32n x 64k output tile per block, 256 threads,
// per-thread 2n x 4k register tile, D chunked by 64 through LDS.
#define BN 32
#define BK 64
#define CD 64
#define PITCH 65  // odd pitch -> <=2-way LDS bank aliasing (free)

__global__ __launch_bounds__(256) void hmlr_main(
        const float* __restrict__ x,
        const float* __restrict__ ws,
        float* __restrict__ out) {
    __shared__ float xs[BN * PITCH];
    __shared__ float ps[BK * PITCH];
    __shared__ float as_[BK * PITCH];

    const float* __restrict__ P = ws + WS_P;
    const float* __restrict__ A = ws + WS_A;

    const int tid = threadIdx.x;
    const int bk  = blockIdx.x & 3;   // K/BK = 4 tiles
    const int bn  = blockIdx.x >> 2;  // N/BN = 64 tiles
    const int n0  = bn * BN;
    const int k0  = bk * BK;
    const int tk  = tid & 15;   // 16 groups x 4k
    const int tn  = tid >> 4;   // 16 groups x 2n

    // staging assignments
    const int xn = tid >> 3;          // 0..31
    const int xd = (tid & 7) * 8;     // 0..56
    const int pk = tid >> 2;          // 0..63
    const int pd = (tid & 3) * 16;    // 0..48

    float xp[2][4] = {{0.f,0.f,0.f,0.f},{0.f,0.f,0.f,0.f}};
    float xa[2][4] = {{0.f,0.f,0.f,0.f},{0.f,0.f,0.f,0.f}};

    for (int dc = 0; dc < DDIM; dc += CD) {
        // ---- stage x tile [32][64] ----
        {
            const float* xg = x + (n0 + xn) * DDIM + dc + xd;
            float4 v0 = *(const float4*)(xg);
            float4 v1 = *(const float4*)(xg + 4);
            float* d = xs + xn * PITCH + xd;
            d[0]=v0.x; d[1]=v0.y; d[2]=v0.z; d[3]=v0.w;
            d[4]=v1.x; d[5]=v1.y; d[6]=v1.z; d[7]=v1.w;
        }
        // ---- stage p,a tiles [64][64] ----
        {
            const float* pg = P + (k0 + pk) * DDIM + dc + pd;
            const float* ag = A + (k0 + pk) * DDIM + dc + pd;
            float* dp = ps  + pk * PITCH + pd;
            float* da = as_ + pk * PITCH + pd;
            #pragma unroll
            for (int q = 0; q < 4; ++q) {
                float4 pv = *(const float4*)(pg + q * 4);
                dp[q*4+0]=pv.x; dp[q*4+1]=pv.y; dp[q*4+2]=pv.z; dp[q*4+3]=pv.w;
                float4 av = *(const float4*)(ag + q * 4);
                da[q*4+0]=av.x; da[q*4+1]=av.y; da[q*4+2]=av.z; da[q*4+3]=av.w;
            }
        }
        __syncthreads();

        const float* xr0 = xs + (2 * tn + 0) * PITCH;
        const float* xr1 = xs + (2 * tn + 1) * PITCH;
        #pragma unroll 4
        for (int dd = 0; dd < CD; ++dd) {
            float x0 = xr0[dd];
            float x1 = xr1[dd];
            #pragma unroll
            for (int j = 0; j < 4; ++j) {
                float pv = ps [(4 * tk + j) * PITCH + dd];
                float av = as_[(4 * tk + j) * PITCH + dd];
                xp[0][j] += x0 * pv;
                xp[1][j] += x1 * pv;
                xa[0][j] += x0 * av;
                xa[1][j] += x1 * av;
            }
        }
        __syncthreads();
    }

    // ---- fused epilogue ----
    const float y2v[2] = { ws[WS_Y2 + n0 + 2*tn + 0],
                           ws[WS_Y2 + n0 + 2*tn + 1] };
    #pragma unroll
    for (int i = 0; i < 2; ++i) {
        const float y2n = y2v[i];
        float r[4];
        #pragma unroll
        for (int j = 0; j < 4; ++j) {
            const int k = k0 + 4 * tk + j;
            float4 sc = ((const float4*)(ws + WS_SC))[k];
            const float p2 = sc.x, pa = sc.y, na = sc.z, kc = sc.w;
            const float xpv = xp[i][j];
            const float xav = xa[i][j];
            // mobius_addition_batch(-p, x): xy = -xp
            const float alpha = 1.0f - 2.0f * xpv + y2n;        // 1 + 2c*xy + c*y2
            const float beta  = 1.0f - p2;                      // 1 - c*||p||^2
            const float gam   = 1.0f - 2.0f * xpv + p2 * y2n;   // denom
            const float gi    = 1.0f / (gam + 1e-5f);
            const float num   = 2.0f * (beta * xav - alpha * pa) * gi;
            const float mob2  = (alpha*alpha*p2 + beta*beta*y2n
                                 - 2.0f*alpha*beta*xpv) * gi * gi;
            const float den   = na * (1.0f - mob2);
            const float z     = num / den;
            // arsinh(z) = log(max(z + sqrt(1+z^2), 1e-5))
            r[j] = kc * logf(fmaxf(z + sqrtf(1.0f + z * z), 1e-5f));
        }
        float4 o = make_float4(r[0], r[1], r[2], r[3]);
        *(float4*)(out + (n0 + 2 * tn + i) * KROWS + k0 + 4 * tk) = o;
    }
}

extern "C" void kernel_launch(void* const* d_in, const int* in_sizes, int n_in,
                              void* d_out, int out_size, void* d_ws, size_t ws_size,
                              hipStream_t stream) {
    (void)in_sizes; (void)n_in; (void)out_size; (void)ws_size;
    const float* x      = (const float*)d_in[0];
    const float* a_vals = (const float*)d_in[1];
    const float* p_vals = (const float*)d_in[2];
    float* ws  = (float*)d_ws;
    float* out = (float*)d_out;

    // prep: 64 blocks for K (4 k per block) + 512 blocks for y2 (4 rows per block)
    hmlr_prep<<<576, 256, 0, stream>>>(x, a_vals, p_vals, ws);
    // main: (N/32) * (K/64) = 64 * 4 = 256 blocks
    hmlr_main<<<256, 256, 0, stream>>>(x, ws, out);
}

// Round 2
// 29.865 us; speedup vs baseline: 1.6315x; 1.6315x over previous
//
#include <hip/hip_runtime.h>
#include <hip/hip_bf16.h>
#include <math.h>

// Problem constants (fixed by the reference setup_inputs)
#define NROWS 2048
#define KROWS 256
#define DDIM  512

typedef __attribute__((ext_vector_type(8))) short short8;
typedef __attribute__((ext_vector_type(4))) float f32x4;

// Workspace layout:
//   PB [K][D] bf16  (p_poincare)      : bytes [0, 256KB)
//   AB [K][D] bf16  (a_poincare)      : bytes [256KB, 512KB)
//   SC [K] float4 {p2, pa, na, kc}    : float offset SC_OFF
//   Y2 [N] float                      : float offset Y2_OFF
#define SC_OFF (KROWS * DDIM)            // in floats (= 512KB of bf16 before it)
#define Y2_OFF (SC_OFF + 4 * KROWS)
// total = 134144 floats ~= 524 KB

__device__ inline unsigned short f2bf(float f) {
    // round-to-nearest-even fp32 -> bf16 (inputs are finite)
    unsigned u = __float_as_uint(f);
    u += 0x7fffu + ((u >> 16) & 1u);
    return (unsigned short)(u >> 16);
}

__device__ inline float wave_reduce_sum(float v) {
    #pragma unroll
    for (int off = 32; off > 0; off >>= 1)
        v += __shfl_xor(v, off, 64);
    return v;
}

// One wave per k (blocks 0..63, 4 k/block) or per x-row (blocks 64..575).
__global__ __launch_bounds__(256) void hmlr_prep(
        const float* __restrict__ x,
        const float* __restrict__ a_vals,
        const float* __restrict__ p_vals,
        float* __restrict__ ws) {
    const int tid  = threadIdx.x;
    const int w    = tid >> 6;
    const int lane = tid & 63;
    const int bid  = blockIdx.x;

    if (bid < 64) {
        const int k = bid * 4 + w;  // 0..255
        const float4* pv4 = (const float4*)(p_vals) + k * (DDIM / 4) + lane * 2;
        const float4* av4 = (const float4*)(a_vals) + k * (DDIM / 4) + lane * 2;
        float4 p0 = pv4[0], p1 = pv4[1];
        float4 a0 = av4[0], a1 = av4[1];

        float pn2 = p0.x*p0.x + p0.y*p0.y + p0.z*p0.z + p0.w*p0.w
                  + p1.x*p1.x + p1.y*p1.y + p1.z*p1.z + p1.w*p1.w;
        float an2 = a0.x*a0.x + a0.y*a0.y + a0.z*a0.z + a0.w*a0.w
                  + a1.x*a1.x + a1.y*a1.y + a1.z*a1.z + a1.w*a1.w;
        float pa0 = p0.x*a0.x + p0.y*a0.y + p0.z*a0.z + p0.w*a0.w
                  + p1.x*a1.x + p1.y*a1.y + p1.z*a1.z + p1.w*a1.w;

        pn2 = wave_reduce_sum(pn2);
        an2 = wave_reduce_sum(an2);
        pa0 = wave_reduce_sum(pa0);

        // expmap0 with c = 1: p = tanh(clamp(||u||,15)) * u / ||u||
        float u     = fmaxf(sqrtf(pn2), 1e-5f);
        float t     = tanhf(fminf(u, 15.0f));
        float scale = t / u;
        float p2    = scale * scale * pn2;       // ||p_poincare||^2
        float conf  = 1.0f - p2;                 // conformal factor (c=1)
        float na    = fmaxf(conf * sqrtf(an2), 1e-7f);  // max(||a_poincare||, 1e-7)
        float pa    = scale * conf * pa0;        // dot(p_poincare, a_poincare)
        float lam   = 2.0f / (1.0f - fminf(p2, 0.9999f)); // 1/c - 1e-4 = 0.9999
        float kc    = lam * na;                  // / sqrt(c) = 1

        // write bf16 P/A rows: lane covers d = lane*8 .. lane*8+7
        unsigned short* PB = (unsigned short*)ws;
        unsigned short* AB = PB + KROWS * DDIM;
        float pf[8] = { scale*p0.x, scale*p0.y, scale*p0.z, scale*p0.w,
                        scale*p1.x, scale*p1.y, scale*p1.z, scale*p1.w };
        float af[8] = { conf*a0.x, conf*a0.y, conf*a0.z, conf*a0.w,
                        conf*a1.x, conf*a1.y, conf*a1.z, conf*a1.w };
        short8 pu, au;
        #pragma unroll
        for (int j = 0; j < 8; ++j) {
            pu[j] = (short)f2bf(pf[j]);
            au[j] = (short)f2bf(af[j]);
        }
        *(short8*)(PB + k * DDIM + lane * 8) = pu;
        *(short8*)(AB + k * DDIM + lane * 8) = au;
        if (lane == 0)
            ((float4*)(ws + SC_OFF))[k] = make_float4(p2, pa, na, kc);
    } else {
        const int row = (bid - 64) * 4 + w;  // 0..2047
        const float4* xv4 = (const float4*)(x) + row * (DDIM / 4) + lane * 2;
        float4 x0 = xv4[0], x1 = xv4[1];
        float s = x0.x*x0.x + x0.y*x0.y + x0.z*x0.z + x0.w*x0.w
                + x1.x*x1.x + x1.y*x1.y + x1.z*x1.z + x1.w*x1.w;
        s = wave_reduce_sum(s);
        if (lane == 0) ws[Y2_OFF + row] = s;
    }
}

// MFMA main kernel: one wave per block; each wave owns a 32(M) x 32(class)
// output tile = 2x2 fragments x 2 maps (xp, xa). No LDS, no barriers.
// A-frag: lane holds X[m0 + mfrag*16 + (lane&15)][d = (lane>>4)*8 + step*32 .. +7]
// B-frag: lane holds P[c0 + cfrag*16 + (lane&15)][same d slice]
// C/D:    col = lane&15, row = (lane>>4)*4 + reg   [m89 verified]
__global__ __launch_bounds__(64) void hmlr_mfma(
        const float* __restrict__ x,
        const float* __restrict__ ws,
        float* __restrict__ out) {
    const int lane = threadIdx.x;
    const int c0 = (blockIdx.x & 7) * 32;   // 256/32 = 8 class tiles
    const int m0 = (blockIdx.x >> 3) * 32;  // 2048/32 = 64 row tiles

    const unsigned short* PB = (const unsigned short*)ws;
    const unsigned short* AB = PB + KROWS * DDIM;
    const float* SC = ws + SC_OFF;
    const float* Y2 = ws + Y2_OFF;

    const int row = lane & 15;
    const int kg  = lane >> 4;

    f32x4 accP[2][2] = {};
    f32x4 accA[2][2] = {};

    const float* xr0 = x + (m0 + row) * DDIM + kg * 8;
    const float* xr1 = xr0 + 16 * DDIM;
    const unsigned short* pb0 = PB + (c0 + row) * DDIM + kg * 8;
    const unsigned short* pb1 = pb0 + 16 * DDIM;
    const unsigned short* ab0 = AB + (c0 + row) * DDIM + kg * 8;
    const unsigned short* ab1 = ab0 + 16 * DDIM;

    #pragma unroll 4
    for (int s = 0; s < 16; ++s) {
        const int d = s * 32;
        float4 v0a = *(const float4*)(xr0 + d);
        float4 v0b = *(const float4*)(xr0 + d + 4);
        float4 v1a = *(const float4*)(xr1 + d);
        float4 v1b = *(const float4*)(xr1 + d + 4);
        short8 af0, af1;
        af0[0] = (short)f2bf(v0a.x); af0[1] = (short)f2bf(v0a.y);
        af0[2] = (short)f2bf(v0a.z); af0[3] = (short)f2bf(v0a.w);
        af0[4] = (short)f2bf(v0b.x); af0[5] = (short)f2bf(v0b.y);
        af0[6] = (short)f2bf(v0b.z); af0[7] = (short)f2bf(v0b.w);
        af1[0] = (short)f2bf(v1a.x); af1[1] = (short)f2bf(v1a.y);
        af1[2] = (short)f2bf(v1a.z); af1[3] = (short)f2bf(v1a.w);
        af1[4] = (short)f2bf(v1b.x); af1[5] = (short)f2bf(v1b.y);
        af1[6] = (short)f2bf(v1b.z); af1[7] = (short)f2bf(v1b.w);

        short8 bp0 = *(const short8*)(pb0 + d);
        short8 bp1 = *(const short8*)(pb1 + d);
        short8 ba0 = *(const short8*)(ab0 + d);
        short8 ba1 = *(const short8*)(ab1 + d);

        accP[0][0] = __builtin_amdgcn_mfma_f32_16x16x32_bf16(af0, bp0, accP[0][0], 0, 0, 0);
        accP[0][1] = __builtin_amdgcn_mfma_f32_16x16x32_bf16(af0, bp1, accP[0][1], 0, 0, 0);
        accP[1][0] = __builtin_amdgcn_mfma_f32_16x16x32_bf16(af1, bp0, accP[1][0], 0, 0, 0);
        accP[1][1] = __builtin_amdgcn_mfma_f32_16x16x32_bf16(af1, bp1, accP[1][1], 0, 0, 0);
        accA[0][0] = __builtin_amdgcn_mfma_f32_16x16x32_bf16(af0, ba0, accA[0][0], 0, 0, 0);
        accA[0][1] = __builtin_amdgcn_mfma_f32_16x16x32_bf16(af0, ba1, accA[0][1], 0, 0, 0);
        accA[1][0] = __builtin_amdgcn_mfma_f32_16x16x32_bf16(af1, ba0, accA[1][0], 0, 0, 0);
        accA[1][1] = __builtin_amdgcn_mfma_f32_16x16x32_bf16(af1, ba1, accA[1][1], 0, 0, 0);
    }

    // ---- fused epilogue ----
    const int rb = kg * 4;
    float y2v[2][4];
    #pragma unroll
    for (int mi = 0; mi < 2; ++mi)
        #pragma unroll
        for (int j = 0; j < 4; ++j)
            y2v[mi][j] = Y2[m0 + mi * 16 + rb + j];

    #pragma unroll
    for (int ci = 0; ci < 2; ++ci) {
        const int c = c0 + ci * 16 + row;
        f32x4 sc = *(const f32x4*)(SC + 4 * c);
        const float p2 = sc[0], pa = sc[1], na = sc[2], kc = sc[3];
        #pragma unroll
        for (int mi = 0; mi < 2; ++mi) {
            #pragma unroll
            for (int j = 0; j < 4; ++j) {
                const float xpv = accP[mi][ci][j];
                const float xav = accA[mi][ci][j];
                const float y2n = y2v[mi][j];
                // mobius_addition_batch(-p, x): xy = -xp
                const float alpha = 1.0f - 2.0f * xpv + y2n;       // 1 + 2c*xy + c*y2
                const float beta  = 1.0f - p2;                     // 1 - c*||p||^2
                const float gam   = 1.0f - 2.0f * xpv + p2 * y2n;  // denom
                const float gi    = 1.0f / (gam + 1e-5f);
                const float num   = 2.0f * (beta * xav - alpha * pa) * gi;
                const float mob2  = (alpha*alpha*p2 + beta*beta*y2n
                                     - 2.0f*alpha*beta*xpv) * gi * gi;
                const float den   = na * (1.0f - mob2);
                const float z     = num / den;
                // arsinh(z) = log(max(z + sqrt(1+z^2), 1e-5))
                const float lg = kc * logf(fmaxf(z + sqrtf(1.0f + z * z), 1e-5f));
                out[(m0 + mi * 16 + rb + j) * KROWS + c] = lg;
            }
        }
    }
}

extern "C" void kernel_launch(void* const* d_in, const int* in_sizes, int n_in,
                              void* d_out, int out_size, void* d_ws, size_t ws_size,
                              hipStream_t stream) {
    (void)in_sizes; (void)n_in; (void)out_size; (void)ws_size;
    const float* x      = (const float*)d_in[0];
    const float* a_vals = (const float*)d_in[1];
    const float* p_vals = (const float*)d_in[2];
    float* ws  = (float*)d_ws;
    float* out = (float*)d_out;

    // prep: 64 blocks for K (4 k/block) + 512 blocks for y2 (4 rows/block)
    hmlr_prep<<<576, 256, 0, stream>>>(x, a_vals, p_vals, ws);
    // main: (2048/32) * (256/32) = 64 * 8 = 512 single-wave blocks
    hmlr_mfma<<<512, 64, 0, stream>>>(x, ws, out);
}

// Round 3
// 23.187 us; speedup vs baseline: 2.1013x; 1.2880x over previous
//
#include <hip/hip_runtime.h>
#include <hip/hip_bf16.h>
#include <math.h>

// Problem constants (fixed by the reference setup_inputs)
#define NROWS 2048
#define KROWS 256
#define DDIM  512

typedef __attribute__((ext_vector_type(8))) short short8;
typedef __attribute__((ext_vector_type(4))) float f32x4;

// Workspace layout (bytes):
//   PB [K][D] bf16 : @0        (262144 B)
//   AB [K][D] bf16 : @262144   (262144 B)
//   SC [K] float4  : @524288   (4096 B)   {p2, pa, na, kc}
//   Y2 [N] float   : @528384   (8192 B)
//   XB [N][D] bf16 : @536576   (2097152 B)   (only if ws_size allows)
#define AB_BYTE   262144
#define SC_FOFF   131072   // float offset
#define Y2_FOFF   132096   // float offset
#define XB_BYTE   536576
#define WS_NEEDED (536576 + 2097152)
#define WS_SMALL  536576   // without XB

__device__ inline unsigned short f2bf(float f) {
    // round-to-nearest-even fp32 -> bf16 (inputs are finite)
    unsigned u = __float_as_uint(f);
    u += 0x7fffu + ((u >> 16) & 1u);
    return (unsigned short)(u >> 16);
}

__device__ inline float wave_reduce_sum(float v) {
    #pragma unroll
    for (int off = 32; off > 0; off >>= 1)
        v += __shfl_xor(v, off, 64);
    return v;
}

// One wave per k (blocks 0..63, 4 k/block) or per x-row (blocks 64..575, 4 rows/block).
template <bool XBWS>
__global__ __launch_bounds__(256) void hmlr_prep(
        const float* __restrict__ x,
        const float* __restrict__ a_vals,
        const float* __restrict__ p_vals,
        float* __restrict__ ws) {
    const int tid  = threadIdx.x;
    const int w    = tid >> 6;
    const int lane = tid & 63;
    const int bid  = blockIdx.x;

    if (bid < 64) {
        const int k = bid * 4 + w;  // 0..255
        const float4* pv4 = (const float4*)(p_vals) + k * (DDIM / 4) + lane * 2;
        const float4* av4 = (const float4*)(a_vals) + k * (DDIM / 4) + lane * 2;
        float4 p0 = pv4[0], p1 = pv4[1];
        float4 a0 = av4[0], a1 = av4[1];

        float pn2 = p0.x*p0.x + p0.y*p0.y + p0.z*p0.z + p0.w*p0.w
                  + p1.x*p1.x + p1.y*p1.y + p1.z*p1.z + p1.w*p1.w;
        float an2 = a0.x*a0.x + a0.y*a0.y + a0.z*a0.z + a0.w*a0.w
                  + a1.x*a1.x + a1.y*a1.y + a1.z*a1.z + a1.w*a1.w;
        float pa0 = p0.x*a0.x + p0.y*a0.y + p0.z*a0.z + p0.w*a0.w
                  + p1.x*a1.x + p1.y*a1.y + p1.z*a1.z + p1.w*a1.w;

        pn2 = wave_reduce_sum(pn2);
        an2 = wave_reduce_sum(an2);
        pa0 = wave_reduce_sum(pa0);

        // expmap0 with c = 1: p = tanh(clamp(||u||,15)) * u / ||u||
        float u     = fmaxf(sqrtf(pn2), 1e-5f);
        float t     = tanhf(fminf(u, 15.0f));
        float scale = t / u;
        float p2    = scale * scale * pn2;       // ||p_poincare||^2
        float conf  = 1.0f - p2;                 // conformal factor (c=1)
        float na    = fmaxf(conf * sqrtf(an2), 1e-7f);  // max(||a_poincare||, 1e-7)
        float pa    = scale * conf * pa0;        // dot(p_poincare, a_poincare)
        float lam   = 2.0f / (1.0f - fminf(p2, 0.9999f)); // 1/c - 1e-4 = 0.9999
        float kc    = lam * na;                  // / sqrt(c) = 1

        unsigned short* PB = (unsigned short*)ws;
        unsigned short* AB = (unsigned short*)((char*)ws + AB_BYTE);
        float pf[8] = { scale*p0.x, scale*p0.y, scale*p0.z, scale*p0.w,
                        scale*p1.x, scale*p1.y, scale*p1.z, scale*p1.w };
        float af[8] = { conf*a0.x, conf*a0.y, conf*a0.z, conf*a0.w,
                        conf*a1.x, conf*a1.y, conf*a1.z, conf*a1.w };
        short8 pu, au;
        #pragma unroll
        for (int j = 0; j < 8; ++j) {
            pu[j] = (short)f2bf(pf[j]);
            au[j] = (short)f2bf(af[j]);
        }
        *(short8*)(PB + k * DDIM + lane * 8) = pu;
        *(short8*)(AB + k * DDIM + lane * 8) = au;
        if (lane == 0)
            ((float4*)(ws + SC_FOFF))[k] = make_float4(p2, pa, na, kc);
    } else {
        const int row = (bid - 64) * 4 + w;  // 0..2047
        const float4* xv4 = (const float4*)(x) + row * (DDIM / 4) + lane * 2;
        float4 x0 = xv4[0], x1 = xv4[1];
        float s = x0.x*x0.x + x0.y*x0.y + x0.z*x0.z + x0.w*x0.w
                + x1.x*x1.x + x1.y*x1.y + x1.z*x1.z + x1.w*x1.w;
        s = wave_reduce_sum(s);
        if (lane == 0) ws[Y2_FOFF + row] = s;
        if (XBWS) {
            unsigned short* XB = (unsigned short*)((char*)ws + XB_BYTE);
            short8 xu;
            xu[0] = (short)f2bf(x0.x); xu[1] = (short)f2bf(x0.y);
            xu[2] = (short)f2bf(x0.z); xu[3] = (short)f2bf(x0.w);
            xu[4] = (short)f2bf(x1.x); xu[5] = (short)f2bf(x1.y);
            xu[6] = (short)f2bf(x1.z); xu[7] = (short)f2bf(x1.w);
            *(short8*)(XB + row * DDIM + lane * 8) = xu;
        }
    }
}

// Main MFMA kernel: one 16(M) x 16(class) tile per wave, 2 MFMA chains (xp, xa).
// 256-thread blocks = 4 waves covering 4 consecutive c-tiles of one m-tile
// (shared X rows -> L1 reuse). No LDS, no barriers.
// A-frag: lane holds X[m0 + (lane&15)][d = (lane>>4)*8 + s*32 .. +7]
// B-frag: lane holds P[c0 + (lane&15)][same d slice]
// C/D:    col = lane&15, row = (lane>>4)*4 + reg   [m89 verified]
template <bool XBWS>
__global__ __launch_bounds__(256) void hmlr_mfma16(
        const float* __restrict__ x,
        const float* __restrict__ ws,
        float* __restrict__ out) {
    const int lane = threadIdx.x & 63;
    const int w    = threadIdx.x >> 6;
    const int mt   = blockIdx.x >> 2;            // 0..127
    const int ct   = (blockIdx.x & 3) * 4 + w;   // 0..15
    const int m0   = mt * 16;
    const int c0   = ct * 16;
    const int row  = lane & 15;
    const int kg   = lane >> 4;

    const unsigned short* PB = (const unsigned short*)ws;
    const unsigned short* AB = (const unsigned short*)((const char*)ws + AB_BYTE);
    const float* SC = ws + SC_FOFF;
    const float* Y2 = ws + Y2_FOFF;

    const unsigned short* pr = PB + (c0 + row) * DDIM + kg * 8;
    const unsigned short* ar = AB + (c0 + row) * DDIM + kg * 8;

    f32x4 accP = {0.f, 0.f, 0.f, 0.f};
    f32x4 accA = {0.f, 0.f, 0.f, 0.f};

    if (XBWS) {
        const unsigned short* XB = (const unsigned short*)((const char*)ws + XB_BYTE);
        const unsigned short* xr = XB + (m0 + row) * DDIM + kg * 8;
        #pragma unroll
        for (int s = 0; s < 16; ++s) {
            short8 xv = *(const short8*)(xr + s * 32);
            short8 pv = *(const short8*)(pr + s * 32);
            short8 av = *(const short8*)(ar + s * 32);
            accP = __builtin_amdgcn_mfma_f32_16x16x32_bf16(xv, pv, accP, 0, 0, 0);
            accA = __builtin_amdgcn_mfma_f32_16x16x32_bf16(xv, av, accA, 0, 0, 0);
        }
    } else {
        const float* xr = x + (m0 + row) * DDIM + kg * 8;
        #pragma unroll
        for (int s = 0; s < 16; ++s) {
            float4 v0 = *(const float4*)(xr + s * 32);
            float4 v1 = *(const float4*)(xr + s * 32 + 4);
            short8 xv;
            xv[0] = (short)f2bf(v0.x); xv[1] = (short)f2bf(v0.y);
            xv[2] = (short)f2bf(v0.z); xv[3] = (short)f2bf(v0.w);
            xv[4] = (short)f2bf(v1.x); xv[5] = (short)f2bf(v1.y);
            xv[6] = (short)f2bf(v1.z); xv[7] = (short)f2bf(v1.w);
            short8 pv = *(const short8*)(pr + s * 32);
            short8 av = *(const short8*)(ar + s * 32);
            accP = __builtin_amdgcn_mfma_f32_16x16x32_bf16(xv, pv, accP, 0, 0, 0);
            accA = __builtin_amdgcn_mfma_f32_16x16x32_bf16(xv, av, accA, 0, 0, 0);
        }
    }

    // ---- fused epilogue ----
    const int c = c0 + row;
    f32x4 sc = *(const f32x4*)(SC + 4 * c);
    const float p2 = sc[0], pa = sc[1], na = sc[2], kc = sc[3];
    #pragma unroll
    for (int j = 0; j < 4; ++j) {
        const int m = m0 + kg * 4 + j;
        const float y2n = Y2[m];
        const float xpv = accP[j];
        const float xav = accA[j];
        // mobius_addition_batch(-p, x): xy = -xp
        const float alpha = 1.0f - 2.0f * xpv + y2n;       // 1 + 2c*xy + c*y2
        const float beta  = 1.0f - p2;                     // 1 - c*||p||^2
        const float gam   = 1.0f - 2.0f * xpv + p2 * y2n;  // denom
        const float gi    = 1.0f / (gam + 1e-5f);
        const float num   = 2.0f * (beta * xav - alpha * pa) * gi;
        const float mob2  = (alpha*alpha*p2 + beta*beta*y2n
                             - 2.0f*alpha*beta*xpv) * gi * gi;
        const float den   = na * (1.0f - mob2);
        const float z     = num / den;
        // arsinh(z) = log(max(z + sqrt(1+z^2), 1e-5))
        out[m * KROWS + c] = kc * logf(fmaxf(z + sqrtf(1.0f + z * z), 1e-5f));
    }
}

extern "C" void kernel_launch(void* const* d_in, const int* in_sizes, int n_in,
                              void* d_out, int out_size, void* d_ws, size_t ws_size,
                              hipStream_t stream) {
    (void)in_sizes; (void)n_in; (void)out_size;
    const float* x      = (const float*)d_in[0];
    const float* a_vals = (const float*)d_in[1];
    const float* p_vals = (const float*)d_in[2];
    float* ws  = (float*)d_ws;
    float* out = (float*)d_out;

    if (ws_size >= (size_t)WS_NEEDED) {
        hmlr_prep<true><<<576, 256, 0, stream>>>(x, a_vals, p_vals, ws);
        // (2048/16) m-tiles * (256/16) c-tiles = 2048 tiles / 4 waves per block
        hmlr_mfma16<true><<<512, 256, 0, stream>>>(x, ws, out);
    } else {
        hmlr_prep<false><<<576, 256, 0, stream>>>(x, a_vals, p_vals, ws);
        hmlr_mfma16<false><<<512, 256, 0, stream>>>(x, ws, out);
    }
}

// Round 4
// 15.852 us; speedup vs baseline: 3.0736x; 1.4627x over previous
//
#include <hip/hip_runtime.h>
#include <hip/hip_bf16.h>
#include <math.h>

// Problem constants (fixed by the reference setup_inputs)
#define NROWS 2048
#define KROWS 256
#define DDIM  512

typedef __attribute__((ext_vector_type(8))) short short8;
typedef __attribute__((ext_vector_type(4))) float f32x4;

// Workspace layout (bytes) — bf16 tensors stored in MFMA-fragment order:
//   chunk index ((tile*16 + s)*64 + kg*16 + r) holds
//   T[tile*16 + r][s*32 + kg*8 .. +8] as short8, so a wave load at
//   base + s*64chunks + lane is 1KB coalesced and fragment-ready.
//   PT [K/16][16][64] short8 : @0        (262144 B)
//   AT [K/16][16][64] short8 : @262144   (262144 B)
//   SC [K] float4            : @524288   (4096 B)   {p2, pa, na, kc}
//   Y2 [N] float             : @528384   (8192 B)
//   XT [N/16][16][64] short8 : @536576   (2097152 B)  (only if ws_size allows)
#define AB_BYTE   262144
#define SC_FOFF   131072   // float offset
#define Y2_FOFF   132096   // float offset
#define XB_BYTE   536576
#define WS_NEEDED (536576 + 2097152)

__device__ inline unsigned short f2bf(float f) {
    // round-to-nearest-even fp32 -> bf16 (inputs are finite)
    unsigned u = __float_as_uint(f);
    u += 0x7fffu + ((u >> 16) & 1u);
    return (unsigned short)(u >> 16);
}

__device__ inline float wave_reduce_sum(float v) {
    #pragma unroll
    for (int off = 32; off > 0; off >>= 1)
        v += __shfl_xor(v, off, 64);
    return v;
}

// One wave per k (blocks 0..63, 4 k/block) or per x-row (blocks 64..575, 4 rows/block).
template <bool XBWS>
__global__ __launch_bounds__(256) void hmlr_prep(
        const float* __restrict__ x,
        const float* __restrict__ a_vals,
        const float* __restrict__ p_vals,
        float* __restrict__ ws) {
    const int tid  = threadIdx.x;
    const int w    = tid >> 6;
    const int lane = tid & 63;
    const int bid  = blockIdx.x;

    if (bid < 64) {
        const int k = bid * 4 + w;  // 0..255
        const float4* pv4 = (const float4*)(p_vals) + k * (DDIM / 4) + lane * 2;
        const float4* av4 = (const float4*)(a_vals) + k * (DDIM / 4) + lane * 2;
        float4 p0 = pv4[0], p1 = pv4[1];
        float4 a0 = av4[0], a1 = av4[1];

        float pn2 = p0.x*p0.x + p0.y*p0.y + p0.z*p0.z + p0.w*p0.w
                  + p1.x*p1.x + p1.y*p1.y + p1.z*p1.z + p1.w*p1.w;
        float an2 = a0.x*a0.x + a0.y*a0.y + a0.z*a0.z + a0.w*a0.w
                  + a1.x*a1.x + a1.y*a1.y + a1.z*a1.z + a1.w*a1.w;
        float pa0 = p0.x*a0.x + p0.y*a0.y + p0.z*a0.z + p0.w*a0.w
                  + p1.x*a1.x + p1.y*a1.y + p1.z*a1.z + p1.w*a1.w;

        pn2 = wave_reduce_sum(pn2);
        an2 = wave_reduce_sum(an2);
        pa0 = wave_reduce_sum(pa0);

        // expmap0 with c = 1: p = tanh(clamp(||u||,15)) * u / ||u||
        float u     = fmaxf(sqrtf(pn2), 1e-5f);
        float t     = tanhf(fminf(u, 15.0f));
        float scale = t / u;
        float p2    = scale * scale * pn2;       // ||p_poincare||^2
        float conf  = 1.0f - p2;                 // conformal factor (c=1)
        float na    = fmaxf(conf * sqrtf(an2), 1e-7f);  // max(||a_poincare||, 1e-7)
        float pa    = scale * conf * pa0;        // dot(p_poincare, a_poincare)
        float lam   = 2.0f / (1.0f - fminf(p2, 0.9999f)); // 1/c - 1e-4 = 0.9999
        float kc    = lam * na;                  // / sqrt(c) = 1

        float pf[8] = { scale*p0.x, scale*p0.y, scale*p0.z, scale*p0.w,
                        scale*p1.x, scale*p1.y, scale*p1.z, scale*p1.w };
        float af[8] = { conf*a0.x, conf*a0.y, conf*a0.z, conf*a0.w,
                        conf*a1.x, conf*a1.y, conf*a1.z, conf*a1.w };
        short8 pu, au;
        #pragma unroll
        for (int j = 0; j < 8; ++j) {
            pu[j] = (short)f2bf(pf[j]);
            au[j] = (short)f2bf(af[j]);
        }
        // fragment-order scatter: s = lane>>2, kg = lane&3, r = k&15
        short8* PT8 = (short8*)ws;
        short8* AT8 = (short8*)((char*)ws + AB_BYTE);
        const int ci = (((k >> 4) * 16 + (lane >> 2)) * 64) + (lane & 3) * 16 + (k & 15);
        PT8[ci] = pu;
        AT8[ci] = au;
        if (lane == 0)
            ((float4*)(ws + SC_FOFF))[k] = make_float4(p2, pa, na, kc);
    } else {
        const int row = (bid - 64) * 4 + w;  // 0..2047
        const float4* xv4 = (const float4*)(x) + row * (DDIM / 4) + lane * 2;
        float4 x0 = xv4[0], x1 = xv4[1];
        float s = x0.x*x0.x + x0.y*x0.y + x0.z*x0.z + x0.w*x0.w
                + x1.x*x1.x + x1.y*x1.y + x1.z*x1.z + x1.w*x1.w;
        s = wave_reduce_sum(s);
        if (lane == 0) ws[Y2_FOFF + row] = s;
        if (XBWS) {
            short8* XT8 = (short8*)((char*)ws + XB_BYTE);
            short8 xu;
            xu[0] = (short)f2bf(x0.x); xu[1] = (short)f2bf(x0.y);
            xu[2] = (short)f2bf(x0.z); xu[3] = (short)f2bf(x0.w);
            xu[4] = (short)f2bf(x1.x); xu[5] = (short)f2bf(x1.y);
            xu[6] = (short)f2bf(x1.z); xu[7] = (short)f2bf(x1.w);
            const int ci = (((row >> 4) * 16 + (lane >> 2)) * 64) + (lane & 3) * 16 + (row & 15);
            XT8[ci] = xu;
        }
    }
}

// Main MFMA kernel: one 16(M) x 16(class) tile per wave, 2 MFMA chains (xp, xa).
// 256-thread blocks = 4 waves covering 4 consecutive c-tiles of one m-tile
// (identical X fragment addresses across waves -> L1 broadcast).
// All fragment loads are coalesced 1KB (fragment-order workspace layout).
// All 16 X fragments preloaded to registers; split accumulators break the
// MFMA dependency chain. No LDS, no barriers.
// C/D: col = lane&15 (class), row = (lane>>4)*4 + reg (m)   [m89 verified]
template <bool XBWS>
__global__ __launch_bounds__(256) void hmlr_mfma16(
        const float* __restrict__ x,
        const float* __restrict__ ws,
        float* __restrict__ out) {
    const int lane = threadIdx.x & 63;
    const int w    = threadIdx.x >> 6;
    const int mt   = blockIdx.x >> 2;            // 0..127
    const int ct   = (blockIdx.x & 3) * 4 + w;   // 0..15
    const int m0   = mt * 16;
    const int c0   = ct * 16;
    const int row  = lane & 15;
    const int kg   = lane >> 4;

    const short8* PT8 = (const short8*)ws;
    const short8* AT8 = (const short8*)((const char*)ws + AB_BYTE);
    const float* SC = ws + SC_FOFF;
    const float* Y2 = ws + Y2_FOFF;

    const short8* pt = PT8 + ct * 16 * 64 + lane;
    const short8* at = AT8 + ct * 16 * 64 + lane;

    // ---- preload all 16 X fragments ----
    short8 xv[16];
    if (XBWS) {
        const short8* xt = (const short8*)((const char*)ws + XB_BYTE) + mt * 16 * 64 + lane;
        #pragma unroll
        for (int s = 0; s < 16; ++s) xv[s] = xt[s * 64];
    } else {
        const float* xr = x + (m0 + row) * DDIM + kg * 8;
        #pragma unroll
        for (int s = 0; s < 16; ++s) {
            float4 v0 = *(const float4*)(xr + s * 32);
            float4 v1 = *(const float4*)(xr + s * 32 + 4);
            short8 xu;
            xu[0] = (short)f2bf(v0.x); xu[1] = (short)f2bf(v0.y);
            xu[2] = (short)f2bf(v0.z); xu[3] = (short)f2bf(v0.w);
            xu[4] = (short)f2bf(v1.x); xu[5] = (short)f2bf(v1.y);
            xu[6] = (short)f2bf(v1.z); xu[7] = (short)f2bf(v1.w);
            xv[s] = xu;
        }
    }

    // ---- P/A load + MFMA loop, split accumulators ----
    f32x4 aP[2] = {{0.f,0.f,0.f,0.f},{0.f,0.f,0.f,0.f}};
    f32x4 aA[2] = {{0.f,0.f,0.f,0.f},{0.f,0.f,0.f,0.f}};
    #pragma unroll
    for (int s = 0; s < 16; ++s) {
        short8 pv = pt[s * 64];
        short8 av = at[s * 64];
        aP[s & 1] = __builtin_amdgcn_mfma_f32_16x16x32_bf16(xv[s], pv, aP[s & 1], 0, 0, 0);
        aA[s & 1] = __builtin_amdgcn_mfma_f32_16x16x32_bf16(xv[s], av, aA[s & 1], 0, 0, 0);
    }
    f32x4 accP = aP[0] + aP[1];
    f32x4 accA = aA[0] + aA[1];

    // ---- fused epilogue ----
    const int c = c0 + row;
    f32x4 sc = *(const f32x4*)(SC + 4 * c);
    const float p2 = sc[0], pa = sc[1], na = sc[2], kc = sc[3];
    #pragma unroll
    for (int j = 0; j < 4; ++j) {
        const int m = m0 + kg * 4 + j;
        const float y2n = Y2[m];
        const float xpv = accP[j];
        const float xav = accA[j];
        // mobius_addition_batch(-p, x): xy = -xp
        const float alpha = 1.0f - 2.0f * xpv + y2n;       // 1 + 2c*xy + c*y2
        const float beta  = 1.0f - p2;                     // 1 - c*||p||^2
        const float gam   = 1.0f - 2.0f * xpv + p2 * y2n;  // denom
        const float gi    = 1.0f / (gam + 1e-5f);
        const float num   = 2.0f * (beta * xav - alpha * pa) * gi;
        const float mob2  = (alpha*alpha*p2 + beta*beta*y2n
                             - 2.0f*alpha*beta*xpv) * gi * gi;
        const float den   = na * (1.0f - mob2);
        const float z     = num / den;
        // arsinh(z) = log(max(z + sqrt(1+z^2), 1e-5))
        out[m * KROWS + c] = kc * logf(fmaxf(z + sqrtf(1.0f + z * z), 1e-5f));
    }
}

extern "C" void kernel_launch(void* const* d_in, const int* in_sizes, int n_in,
                              void* d_out, int out_size, void* d_ws, size_t ws_size,
                              hipStream_t stream) {
    (void)in_sizes; (void)n_in; (void)out_size;
    const float* x      = (const float*)d_in[0];
    const float* a_vals = (const float*)d_in[1];
    const float* p_vals = (const float*)d_in[2];
    float* ws  = (float*)d_ws;
    float* out = (float*)d_out;

    if (ws_size >= (size_t)WS_NEEDED) {
        hmlr_prep<true><<<576, 256, 0, stream>>>(x, a_vals, p_vals, ws);
        // (2048/16) m-tiles * (256/16) c-tiles = 2048 tiles / 4 waves per block
        hmlr_mfma16<true><<<512, 256, 0, stream>>>(x, ws, out);
    } else {
        hmlr_prep<false><<<576, 256, 0, stream>>>(x, a_vals, p_vals, ws);
        hmlr_mfma16<false><<<512, 256, 0, stream>>>(x, ws, out);
    }
}